// Round 10
// baseline (211.753 us; speedup 1.0000x reference)
//
#include <hip/hip_runtime.h>
#include <math.h>

#define KDIM 64
#define TDIM 100
#define VDIM 10000
#define NV4  2500            // VDIM / 4
#define BLOCK 640            // 10 waves
#define NWAVE 10
#define HALFS 1280           // vf4 slots per half-row
#define CHUNK 5
#define NCHUNK (TDIM / CHUNK)
#define TAIL  (NV4 - 3 * BLOCK)   // 580: guard for 4th slot / 2nd instr of half1

#define INV1 (1.0f / (1.0f + 1e-6f))
#define INVD (1.0f / (0.005f + 1e-6f))
#define LOGD (-5.2983173665480363f)   // log(0.005f)

typedef float vf4 __attribute__((ext_vector_type(4)));

__device__ __forceinline__ float wave_red_sum(float v) {
#pragma unroll
    for (int m = 32; m >= 1; m >>= 1) v += __shfl_xor(v, m, 64);
    return v;
}

// async global->LDS DMA, 16B per lane, zero VGPR cost, tracked by vmcnt
__device__ __forceinline__ void async16(const vf4* g, vf4* l) {
    __builtin_amdgcn_global_load_lds(
        (const __attribute__((address_space(1))) void*)(const void*)g,
        (__attribute__((address_space(3))) void*)(void*)l, 16, 0, 0);
}

__device__ __forceinline__ void waitv6() { asm volatile("s_waitcnt vmcnt(6)" ::: "memory"); }
__device__ __forceinline__ void waitv0() { asm volatile("s_waitcnt vmcnt(0)" ::: "memory"); }
// barrier that does NOT drain vmcnt (prefetch survives)
__device__ __forceinline__ void raw_barrier() { asm volatile("s_barrier" ::: "memory"); }
// barrier ordering our own LDS reads/writes (WAR protection before re-DMA)
__device__ __forceinline__ void lds_barrier() {
    asm volatile("s_waitcnt lgkmcnt(0)\n\ts_barrier" ::: "memory");
}

// issue the 6 DMA instrs/wave for one half-row into staging buffer st
template <int HR>
__device__ __forceinline__ void dma_half(const float* mu_row, const float* ls_row,
                                         const float* ep_row, vf4* st, int tid) {
#pragma unroll
    for (int j = 0; j < 2; ++j) {
        const int s    = tid + j * BLOCK;       // slot within half [0,1280)
        const int slot = HR * HALFS + s;        // slot within row
        if (HR == 0 || slot < NV4) {            // only half1/j=1 is partially masked
            async16((const vf4*)mu_row + slot, st + 0 * HALFS + s);
            async16((const vf4*)ls_row + slot, st + 1 * HALFS + s);
            async16((const vf4*)ep_row + slot, st + 2 * HALFS + s);
        }
    }
}

// beta + optional KL + exp-sum for one vf4; updates persistent B in place
__device__ __forceinline__ void consume(const vf4 m, const vf4 l, const vf4 e,
                                        vf4& B, const bool first, const bool skip,
                                        float& klacc, float& lsum) {
    const float sx = __expf(0.5f * l.x), sy = __expf(0.5f * l.y),
                sz = __expf(0.5f * l.z), sw = __expf(0.5f * l.w);
    vf4 b;
    b.x = fmaf(sx, e.x, m.x);
    b.y = fmaf(sy, e.y, m.y);
    b.z = fmaf(sz, e.z, m.z);
    b.w = fmaf(sw, e.w, m.w);
    if (first) {
        klacc += (sx * sx + m.x * m.x) * INV1 - 1.0f - l.x;
        klacc += (sy * sy + m.y * m.y) * INV1 - 1.0f - l.y;
        klacc += (sz * sz + m.z * m.z) * INV1 - 1.0f - l.z;
        klacc += (sw * sw + m.w * m.w) * INV1 - 1.0f - l.w;
    } else if (!skip) {
        const float dx = m.x - B.x, dy = m.y - B.y, dz = m.z - B.z, dw = m.w - B.w;
        klacc += (sx * sx + dx * dx) * INVD - 1.0f + LOGD - l.x;
        klacc += (sy * sy + dy * dy) * INVD - 1.0f + LOGD - l.y;
        klacc += (sz * sz + dz * dz) * INVD - 1.0f + LOGD - l.z;
        klacc += (sw * sw + dw * dw) * INVD - 1.0f + LOGD - l.w;
    }
    B = b;
    lsum += __expf(b.x) + __expf(b.y) + __expf(b.z) + __expf(b.w);
}

__device__ __forceinline__ void kl_step(const vf4 m, const vf4 l, const vf4 B,
                                        float& klacc) {
    const float sx = __expf(0.5f * l.x), sy = __expf(0.5f * l.y),
                sz = __expf(0.5f * l.z), sw = __expf(0.5f * l.w);
    const float dx = m.x - B.x, dy = m.y - B.y, dz = m.z - B.z, dw = m.w - B.w;
    klacc += (sx * sx + dx * dx) * INVD - 1.0f + LOGD - l.x;
    klacc += (sy * sy + dy * dy) * INVD - 1.0f + LOGD - l.y;
    klacc += (sz * sz + dz * dz) * INVD - 1.0f + LOGD - l.z;
    klacc += (sw * sw + dw * dw) * INVD - 1.0f + LOGD - l.w;
}

__global__ __launch_bounds__(BLOCK) void fused_beta_softmax_kl(
    const float* __restrict__ mu_q,   // [K, T, V]
    const float* __restrict__ lsq,    // [K, T, V]
    const float* __restrict__ eps,    // [T, K, V]
    float* __restrict__ out,          // [T, K, V]
    float* __restrict__ kl)           // scalar (pre-zeroed)
{
    __shared__ vf4 stage[2][3 * HALFS];   // 120 KB: {mu,lsq,eps} x 2 half-buffers
    __shared__ float red[2][NWAVE];
    __shared__ float kred[NWAVE];

    const int tid = threadIdx.x;
    const int bid = blockIdx.x;
    const int k   = bid / NCHUNK;
    const int c   = bid % NCHUNK;
    const int t0  = c * CHUNK;
    const int tend = t0 + CHUNK;
    const bool epi = (tend < TDIM);

    float klacc = 0.0f;
    vf4 B0, B1, B2, B3;                   // beta of current row (16 VGPR, static idx)

    const float* mu_row = mu_q + ((size_t)k * TDIM + t0) * VDIM;
    const float* ls_row = lsq  + ((size_t)k * TDIM + t0) * VDIM;
    const float* ep_row = eps  + ((size_t)t0 * KDIM + k) * VDIM;

    // ---- prologue: DMA both halves of row t0 (12 instrs/wave in flight) ----
    dma_half<0>(mu_row, ls_row, ep_row, stage[0], tid);
    dma_half<1>(mu_row, ls_row, ep_row, stage[1], tid);

    for (int r = 0; r < CHUNK; ++r) {
        const int t = t0 + r;
        const bool first = (t == 0);
        const bool skip  = (r == 0) && (t0 != 0);  // prev block owns this KL term
        const bool more  = (r + 1 < CHUNK);
        const float* mu_n = mu_row + VDIM;         // next row (k-major: +V)
        const float* ls_n = ls_row + VDIM;
        const float* ep_n = ep_row + (size_t)KDIM * VDIM;  // t-major: +K*V
        float lsum = 0.0f;

        // ---- half0: wait (newest 6 = half1's DMAs), consume, re-DMA ----
        waitv6();
        raw_barrier();
        {
            const vf4* S = stage[0];
            const vf4 m0 = S[tid],          l0 = S[HALFS + tid],          e0 = S[2 * HALFS + tid];
            const vf4 m1 = S[tid + BLOCK],  l1 = S[HALFS + tid + BLOCK],  e1 = S[2 * HALFS + tid + BLOCK];
            consume(m0, l0, e0, B0, first, skip, klacc, lsum);
            consume(m1, l1, e1, B1, first, skip, klacc, lsum);
        }
        lds_barrier();                              // all waves done reading stage[0]
        if (more) dma_half<0>(mu_n, ls_n, ep_n, stage[0], tid);

        // ---- half1: wait (newest 6 = next half0's DMAs; last row: drain) ----
        if (more) waitv6(); else waitv0();
        raw_barrier();
        {
            const vf4* S = stage[1];
            const vf4 m0 = S[tid],         l0 = S[HALFS + tid],         e0 = S[2 * HALFS + tid];
            consume(m0, l0, e0, B2, first, skip, klacc, lsum);
            if (tid < TAIL) {
                const vf4 m1 = S[tid + BLOCK], l1 = S[HALFS + tid + BLOCK], e1 = S[2 * HALFS + tid + BLOCK];
                consume(m1, l1, e1, B3, first, skip, klacc, lsum);
            }
        }

        // ---- row reduction + output; then prefetch next half1 ----
        float ws = wave_red_sum(lsum);
        if ((tid & 63) == 0) red[r & 1][tid >> 6] = ws;
        lds_barrier();                              // red visible + stage[1] WAR-safe
        float rowsum = 0.0f;
#pragma unroll
        for (int w = 0; w < NWAVE; ++w) rowsum += red[r & 1][w];
        const float invs = 1.0f / rowsum;

        vf4* o4p = reinterpret_cast<vf4*>(out + ((size_t)t * KDIM + k) * VDIM);
        {
            vf4 o;
            o.x = __expf(B0.x) * invs; o.y = __expf(B0.y) * invs;
            o.z = __expf(B0.z) * invs; o.w = __expf(B0.w) * invs;
            __builtin_nontemporal_store(o, &o4p[tid]);
            o.x = __expf(B1.x) * invs; o.y = __expf(B1.y) * invs;
            o.z = __expf(B1.z) * invs; o.w = __expf(B1.w) * invs;
            __builtin_nontemporal_store(o, &o4p[tid + BLOCK]);
            o.x = __expf(B2.x) * invs; o.y = __expf(B2.y) * invs;
            o.z = __expf(B2.z) * invs; o.w = __expf(B2.w) * invs;
            __builtin_nontemporal_store(o, &o4p[HALFS + tid]);
            if (tid < TAIL) {
                o.x = __expf(B3.x) * invs; o.y = __expf(B3.y) * invs;
                o.z = __expf(B3.z) * invs; o.w = __expf(B3.w) * invs;
                __builtin_nontemporal_store(o, &o4p[HALFS + tid + BLOCK]);
            }
        }
        // issue LAST so the counted waits see it as the newest group
        if (more) dma_half<1>(mu_n, ls_n, ep_n, stage[1], tid);

        mu_row = mu_n; ls_row = ls_n; ep_row = ep_n;
    }

    // ---- forward-handoff KL for row tend (plain loads, once per block) ----
    if (epi) {
        const float* mu_e = mu_q + ((size_t)k * TDIM + tend) * VDIM;
        const float* ls_e = lsq  + ((size_t)k * TDIM + tend) * VDIM;
        const vf4* m4p = (const vf4*)mu_e;
        const vf4* l4p = (const vf4*)ls_e;
        kl_step(m4p[tid], l4p[tid], B0, klacc);
        kl_step(m4p[tid + BLOCK], l4p[tid + BLOCK], B1, klacc);
        kl_step(m4p[HALFS + tid], l4p[HALFS + tid], B2, klacc);
        if (tid < TAIL)
            kl_step(m4p[HALFS + tid + BLOCK], l4p[HALFS + tid + BLOCK], B3, klacc);
    }

    // ---- KL block reduction + one atomic per block ----
    float wk = wave_red_sum(klacc);
    __syncthreads();
    if ((tid & 63) == 0) kred[tid >> 6] = wk;
    __syncthreads();
    if (tid == 0) {
        float tot = 0.0f;
#pragma unroll
        for (int w = 0; w < NWAVE; ++w) tot += kred[w];
        atomicAdd(kl, 0.5f * tot);
    }
}

extern "C" void kernel_launch(void* const* d_in, const int* in_sizes, int n_in,
                              void* d_out, int out_size, void* d_ws, size_t ws_size,
                              hipStream_t stream) {
    const float* mu_q = (const float*)d_in[0];  // [K,T,V]
    const float* lsq  = (const float*)d_in[1];  // [K,T,V]
    const float* eps  = (const float*)d_in[2];  // [T,K,V]
    float* out = (float*)d_out;                 // [T,K,V] softmax, then 1 float KL
    float* kl  = out + (size_t)TDIM * KDIM * VDIM;

    // zero the KL accumulator each launch (graph-capture-safe)
    (void)hipMemsetAsync(kl, 0, sizeof(float), stream);

    dim3 grid(KDIM * NCHUNK);
    fused_beta_softmax_kl<<<grid, BLOCK, 0, stream>>>(mu_q, lsq, eps, out, kl);
}

// Round 11
// 203.697 us; speedup vs baseline: 1.0395x; 1.0395x over previous
//
#include <hip/hip_runtime.h>
#include <math.h>

#define KDIM 64
#define TDIM 100
#define VDIM 10000
#define NV4  2500            // VDIM / 4
#define BLOCK 512
#define NWAVE (BLOCK / 64)   // 8
#define VPT 5                // ceil(NV4 / BLOCK)
#define CHUNK 5
#define NCHUNK (TDIM / CHUNK)  // 20

#define INV1 (1.0f / (1.0f + 1e-6f))
#define INVD (1.0f / (0.005f + 1e-6f))
#define LOGD (-5.2983173665480363f)   // log(0.005f)

// native clang vector type: __builtin_nontemporal_* accepts this, identical
// layout/codegen (global_load_dwordx4) to HIP's float4.
typedef float vf4 __attribute__((ext_vector_type(4)));

// guard: jj < VPT-1 rows are always in range (tid + 3*512 <= 2047 < 2500)
#define INRANGE(jj, idx) ((jj) < VPT - 1 || (idx) < NV4)

__device__ __forceinline__ float wave_red_sum(float v) {
#pragma unroll
    for (int m = 32; m >= 1; m >>= 1) v += __shfl_xor(v, m, 64);
    return v;
}

// barrier that does NOT drain vmcnt: global loads/stores stay in flight.
// lgkmcnt(0) commits our ds_write of the reduction slot before the barrier.
__device__ __forceinline__ void lds_barrier() {
    asm volatile("s_waitcnt lgkmcnt(0)\n\ts_barrier" ::: "memory");
}

__global__ __launch_bounds__(BLOCK, 4) void fused_beta_softmax_kl(
    const float* __restrict__ mu_q,   // [K, T, V]
    const float* __restrict__ lsq,    // [K, T, V]
    const float* __restrict__ eps,    // [T, K, V]
    float* __restrict__ out,          // [T, K, V]
    float* __restrict__ kl)           // scalar (pre-zeroed)
{
    __shared__ vf4 bprev[NV4];        // 40 KB: beta of current row, thread-private slots
    __shared__ float red[2][NWAVE];
    __shared__ float kred[NWAVE];

    const int tid = threadIdx.x;
    const int bid = blockIdx.x;
    // XCD-affinity swizzle: dispatch round-robins XCD = bid % 8. Map all 20
    // chunks of one k to the same XCD so the handoff row (t0+5), re-read by
    // this block and freshly-read by chunk c+1, is an L2 hit. Bijective:
    // 1280 = 8 xcd * (8 k * 20 c).
    const int xcd = bid & 7;
    const int idx8 = bid >> 3;        // 0..159
    const int k   = xcd * 8 + idx8 / NCHUNK;
    const int c   = idx8 % NCHUNK;
    const int t0  = c * CHUNK;
    const int tend = t0 + CHUNK;
    const bool epi = (tend < TDIM);   // this block computes KL term of row tend too

    float klacc = 0.0f;
    vf4 M[VPT], L[VPT], E[VPT];

    for (int t = t0; t < tend; ++t) {
        const size_t po = ((size_t)k * TDIM + t) * VDIM;
        const size_t eo = ((size_t)t * KDIM + k) * VDIM;
        const vf4* m4p = reinterpret_cast<const vf4*>(mu_q + po);
        const vf4* l4p = reinterpret_cast<const vf4*>(lsq + po);
        const vf4* e4p = reinterpret_cast<const vf4*>(eps + eo);
        const bool first = (t == 0);
        const bool skip  = (t == t0) && (t0 != 0);   // prev block owns this KL term

        // ---- stage all 15 global loads ----
#pragma unroll
        for (int jj = 0; jj < VPT; ++jj) {
            const int idx = tid + jj * BLOCK;
            if (INRANGE(jj, idx)) {
                M[jj] = m4p[idx];
                L[jj] = l4p[idx];
                E[jj] = __builtin_nontemporal_load(&e4p[idx]);  // pure stream
            }
        }

        // ---- consume: beta -> LDS, KL vs old LDS beta, exp-sum ----
        float lsum = 0.0f;
#pragma unroll
        for (int jj = 0; jj < VPT; ++jj) {
            const int idx = tid + jj * BLOCK;
            if (INRANGE(jj, idx)) {
                const vf4 m = M[jj], l = L[jj], e = E[jj];
                // s = exp(l/2); exp(l) = s*s (one transcendental saved)
                const float sx = __expf(0.5f * l.x), sy = __expf(0.5f * l.y),
                            sz = __expf(0.5f * l.z), sw = __expf(0.5f * l.w);
                vf4 b;
                b.x = fmaf(sx, e.x, m.x);
                b.y = fmaf(sy, e.y, m.y);
                b.z = fmaf(sz, e.z, m.z);
                b.w = fmaf(sw, e.w, m.w);
                if (first) {
                    klacc += (sx * sx + m.x * m.x) * INV1 - 1.0f - l.x;
                    klacc += (sy * sy + m.y * m.y) * INV1 - 1.0f - l.y;
                    klacc += (sz * sz + m.z * m.z) * INV1 - 1.0f - l.z;
                    klacc += (sw * sw + m.w * m.w) * INV1 - 1.0f - l.w;
                } else if (!skip) {
                    const vf4 p = bprev[idx];
                    const float dx = m.x - p.x, dy = m.y - p.y,
                                dz = m.z - p.z, dw = m.w - p.w;
                    klacc += (sx * sx + dx * dx) * INVD - 1.0f + LOGD - l.x;
                    klacc += (sy * sy + dy * dy) * INVD - 1.0f + LOGD - l.y;
                    klacc += (sz * sz + dz * dz) * INVD - 1.0f + LOGD - l.z;
                    klacc += (sw * sw + dw * dw) * INVD - 1.0f + LOGD - l.w;
                }
                bprev[idx] = b;
                lsum += __expf(b.x) + __expf(b.y) + __expf(b.z) + __expf(b.w);
            }
        }

        // ---- exp-sum block reduction (vmcnt-preserving barrier) ----
        const int slot = t & 1;
        float ws = wave_red_sum(lsum);
        if ((tid & 63) == 0) red[slot][tid >> 6] = ws;
        lds_barrier();
        float rowsum = 0.0f;
#pragma unroll
        for (int w = 0; w < NWAVE; ++w) rowsum += red[slot][w];
        const float invs = 1.0f / rowsum;

        // ---- write softmax = exp(beta) * invs, beta re-read from LDS ----
        vf4* o4p = reinterpret_cast<vf4*>(out + ((size_t)t * KDIM + k) * VDIM);
#pragma unroll
        for (int jj = 0; jj < VPT; ++jj) {
            const int idx = tid + jj * BLOCK;
            if (INRANGE(jj, idx)) {
                const vf4 b = bprev[idx];
                vf4 o;
                o.x = __expf(b.x) * invs;
                o.y = __expf(b.y) * invs;
                o.z = __expf(b.z) * invs;
                o.w = __expf(b.w) * invs;
                __builtin_nontemporal_store(o, &o4p[idx]);  // streaming output
            }
        }
        // bprev slots are thread-private; red double-buffered -> one barrier/row
    }

    // ---- forward-handoff KL for row tend (mu/lsq only; L2-hot via swizzle) ----
    if (epi) {
        const size_t po = ((size_t)k * TDIM + tend) * VDIM;
        const vf4* m4p = reinterpret_cast<const vf4*>(mu_q + po);
        const vf4* l4p = reinterpret_cast<const vf4*>(lsq + po);
#pragma unroll
        for (int jj = 0; jj < VPT; ++jj) {
            const int idx = tid + jj * BLOCK;
            if (INRANGE(jj, idx)) { M[jj] = m4p[idx]; L[jj] = l4p[idx]; }
        }
#pragma unroll
        for (int jj = 0; jj < VPT; ++jj) {
            const int idx = tid + jj * BLOCK;
            if (INRANGE(jj, idx)) {
                const vf4 m = M[jj], l = L[jj];
                const vf4 p = bprev[idx];
                const float sx = __expf(0.5f * l.x), sy = __expf(0.5f * l.y),
                            sz = __expf(0.5f * l.z), sw = __expf(0.5f * l.w);
                const float dx = m.x - p.x, dy = m.y - p.y,
                            dz = m.z - p.z, dw = m.w - p.w;
                klacc += (sx * sx + dx * dx) * INVD - 1.0f + LOGD - l.x;
                klacc += (sy * sy + dy * dy) * INVD - 1.0f + LOGD - l.y;
                klacc += (sz * sz + dz * dz) * INVD - 1.0f + LOGD - l.z;
                klacc += (sw * sw + dw * dw) * INVD - 1.0f + LOGD - l.w;
            }
        }
    }

    // ---- KL block reduction + one atomic per block ----
    float wk = wave_red_sum(klacc);
    __syncthreads();
    if ((tid & 63) == 0) kred[tid >> 6] = wk;
    __syncthreads();
    if (tid == 0) {
        float tot = 0.0f;
#pragma unroll
        for (int w = 0; w < NWAVE; ++w) tot += kred[w];
        atomicAdd(kl, 0.5f * tot);
    }
}

extern "C" void kernel_launch(void* const* d_in, const int* in_sizes, int n_in,
                              void* d_out, int out_size, void* d_ws, size_t ws_size,
                              hipStream_t stream) {
    const float* mu_q = (const float*)d_in[0];  // [K,T,V]
    const float* lsq  = (const float*)d_in[1];  // [K,T,V]
    const float* eps  = (const float*)d_in[2];  // [T,K,V]
    float* out = (float*)d_out;                 // [T,K,V] softmax, then 1 float KL
    float* kl  = out + (size_t)TDIM * KDIM * VDIM;

    // zero the KL accumulator each launch (graph-capture-safe)
    (void)hipMemsetAsync(kl, 0, sizeof(float), stream);

    dim3 grid(KDIM * NCHUNK);
    fused_beta_softmax_kl<<<grid, BLOCK, 0, stream>>>(mu_q, lsq, eps, out, kl);
}

// Round 12
// 200.258 us; speedup vs baseline: 1.0574x; 1.0172x over previous
//
#include <hip/hip_runtime.h>
#include <math.h>

#define KDIM 64
#define TDIM 100
#define VDIM 10000
#define NV4  2500            // VDIM / 4
#define BLOCK 512
#define NWAVE (BLOCK / 64)   // 8
#define VPT 5                // ceil(NV4 / BLOCK)
#define CHUNK 5
#define NCHUNK (TDIM / CHUNK)

#define INV1 (1.0f / (1.0f + 1e-6f))
#define INVD (1.0f / (0.005f + 1e-6f))
#define LOGD (-5.2983173665480363f)   // log(0.005f)

// native clang vector type: __builtin_nontemporal_* accepts this, and it has
// identical layout/codegen (global_load_dwordx4) to HIP's float4.
typedef float vf4 __attribute__((ext_vector_type(4)));

// guard: jj < VPT-1 rows are always in range (tid + 3*512 <= 2047 < 2500)
#define INRANGE(jj, idx) ((jj) < VPT - 1 || (idx) < NV4)

__device__ __forceinline__ float wave_red_sum(float v) {
#pragma unroll
    for (int m = 32; m >= 1; m >>= 1) v += __shfl_xor(v, m, 64);
    return v;
}

// barrier that does NOT drain vmcnt: stores/loads stay in flight.
// lgkmcnt(0) commits our ds_write of the reduction slot before the barrier.
__device__ __forceinline__ void lds_barrier() {
    asm volatile("s_waitcnt lgkmcnt(0)\n\ts_barrier" ::: "memory");
}

__global__ __launch_bounds__(BLOCK, 4) void fused_beta_softmax_kl(
    const float* __restrict__ mu_q,   // [K, T, V]
    const float* __restrict__ lsq,    // [K, T, V]
    const float* __restrict__ eps,    // [T, K, V]
    float* __restrict__ out,          // [T, K, V]
    float* __restrict__ kl)           // scalar (pre-zeroed)
{
    __shared__ vf4 bprev[NV4];        // 40 KB: beta of current row, thread-private slots
    __shared__ float red[2][NWAVE];
    __shared__ float kred[NWAVE];

    const int tid = threadIdx.x;
    const int bid = blockIdx.x;
    const int k   = bid / NCHUNK;
    const int c   = bid % NCHUNK;
    const int t0  = c * CHUNK;
    const int tend = t0 + CHUNK;
    const bool epi = (tend < TDIM);   // this block computes KL term of row tend too

    float klacc = 0.0f;
    vf4 M[VPT], L[VPT], E[VPT];       // staging registers

    for (int t = t0; t < tend; ++t) {
        const size_t po = ((size_t)k * TDIM + t) * VDIM;
        const size_t eo = ((size_t)t * KDIM + k) * VDIM;
        const vf4* m4p = reinterpret_cast<const vf4*>(mu_q + po);
        const vf4* l4p = reinterpret_cast<const vf4*>(lsq + po);
        const vf4* e4p = reinterpret_cast<const vf4*>(eps + eo);
        const bool first = (t == 0);
        const bool skip  = (t == t0) && (t0 != 0);   // prev block owns this KL term

        // ---- stage all 15 global loads back-to-back ----
#pragma unroll
        for (int jj = 0; jj < VPT; ++jj) {
            const int idx = tid + jj * BLOCK;
            if (INRANGE(jj, idx)) {
                M[jj] = m4p[idx];
                L[jj] = l4p[idx];
                E[jj] = __builtin_nontemporal_load(&e4p[idx]);  // pure stream
            }
        }

        // ---- consume: beta -> LDS, KL vs old LDS beta, exp-sum ----
        float lsum = 0.0f;
#pragma unroll
        for (int jj = 0; jj < VPT; ++jj) {
            const int idx = tid + jj * BLOCK;
            if (INRANGE(jj, idx)) {
                const vf4 m = M[jj], l = L[jj], e = E[jj];
                vf4 b;
                b.x = fmaf(__expf(0.5f * l.x), e.x, m.x);
                b.y = fmaf(__expf(0.5f * l.y), e.y, m.y);
                b.z = fmaf(__expf(0.5f * l.z), e.z, m.z);
                b.w = fmaf(__expf(0.5f * l.w), e.w, m.w);
                if (first) {
                    klacc += (__expf(l.x) + m.x * m.x) * INV1 - 1.0f - l.x;
                    klacc += (__expf(l.y) + m.y * m.y) * INV1 - 1.0f - l.y;
                    klacc += (__expf(l.z) + m.z * m.z) * INV1 - 1.0f - l.z;
                    klacc += (__expf(l.w) + m.w * m.w) * INV1 - 1.0f - l.w;
                } else if (!skip) {
                    const vf4 p = bprev[idx];
                    const float dx = m.x - p.x, dy = m.y - p.y,
                                dz = m.z - p.z, dw = m.w - p.w;
                    klacc += (__expf(l.x) + dx * dx) * INVD - 1.0f + LOGD - l.x;
                    klacc += (__expf(l.y) + dy * dy) * INVD - 1.0f + LOGD - l.y;
                    klacc += (__expf(l.z) + dz * dz) * INVD - 1.0f + LOGD - l.z;
                    klacc += (__expf(l.w) + dw * dw) * INVD - 1.0f + LOGD - l.w;
                }
                bprev[idx] = b;
                lsum += __expf(b.x) + __expf(b.y) + __expf(b.z) + __expf(b.w);
            }
        }

        // ---- exp-sum block reduction (vmcnt-preserving barrier) ----
        const int slot = t & 1;
        float ws = wave_red_sum(lsum);
        if ((tid & 63) == 0) red[slot][tid >> 6] = ws;
        lds_barrier();
        float rowsum = 0.0f;
#pragma unroll
        for (int w = 0; w < NWAVE; ++w) rowsum += red[slot][w];
        const float invs = 1.0f / rowsum;

        // ---- write softmax = exp(beta) * invs, beta re-read from LDS ----
        vf4* o4p = reinterpret_cast<vf4*>(out + ((size_t)t * KDIM + k) * VDIM);
#pragma unroll
        for (int jj = 0; jj < VPT; ++jj) {
            const int idx = tid + jj * BLOCK;
            if (INRANGE(jj, idx)) {
                const vf4 b = bprev[idx];
                vf4 o;
                o.x = __expf(b.x) * invs;
                o.y = __expf(b.y) * invs;
                o.z = __expf(b.z) * invs;
                o.w = __expf(b.w) * invs;
                __builtin_nontemporal_store(o, &o4p[idx]);  // streaming output
            }
        }
        // bprev slots are thread-private; red double-buffered -> one barrier/row
    }

    // ---- forward-handoff KL for row tend (mu/lsq only, cache-friendly loads) ----
    if (epi) {
        const size_t po = ((size_t)k * TDIM + tend) * VDIM;
        const vf4* m4p = reinterpret_cast<const vf4*>(mu_q + po);
        const vf4* l4p = reinterpret_cast<const vf4*>(lsq + po);
#pragma unroll
        for (int jj = 0; jj < VPT; ++jj) {
            const int idx = tid + jj * BLOCK;
            if (INRANGE(jj, idx)) { M[jj] = m4p[idx]; L[jj] = l4p[idx]; }
        }
#pragma unroll
        for (int jj = 0; jj < VPT; ++jj) {
            const int idx = tid + jj * BLOCK;
            if (INRANGE(jj, idx)) {
                const vf4 m = M[jj], l = L[jj];
                const vf4 p = bprev[idx];
                const float dx = m.x - p.x, dy = m.y - p.y,
                            dz = m.z - p.z, dw = m.w - p.w;
                klacc += (__expf(l.x) + dx * dx) * INVD - 1.0f + LOGD - l.x;
                klacc += (__expf(l.y) + dy * dy) * INVD - 1.0f + LOGD - l.y;
                klacc += (__expf(l.z) + dz * dz) * INVD - 1.0f + LOGD - l.z;
                klacc += (__expf(l.w) + dw * dw) * INVD - 1.0f + LOGD - l.w;
            }
        }
    }

    // ---- KL block reduction + one atomic per block ----
    float wk = wave_red_sum(klacc);
    __syncthreads();
    if ((tid & 63) == 0) kred[tid >> 6] = wk;
    __syncthreads();
    if (tid == 0) {
        float tot = 0.0f;
#pragma unroll
        for (int w = 0; w < NWAVE; ++w) tot += kred[w];
        atomicAdd(kl, 0.5f * tot);
    }
}

extern "C" void kernel_launch(void* const* d_in, const int* in_sizes, int n_in,
                              void* d_out, int out_size, void* d_ws, size_t ws_size,
                              hipStream_t stream) {
    const float* mu_q = (const float*)d_in[0];  // [K,T,V]
    const float* lsq  = (const float*)d_in[1];  // [K,T,V]
    const float* eps  = (const float*)d_in[2];  // [T,K,V]
    float* out = (float*)d_out;                 // [T,K,V] softmax, then 1 float KL
    float* kl  = out + (size_t)TDIM * KDIM * VDIM;

    // zero the KL accumulator each launch (graph-capture-safe)
    (void)hipMemsetAsync(kl, 0, sizeof(float), stream);

    dim3 grid(KDIM * NCHUNK);
    fused_beta_softmax_kl<<<grid, BLOCK, 0, stream>>>(mu_q, lsq, eps, out, kl);
}